// Round 10
// baseline (7555.386 us; speedup 1.0000x reference)
//
#include <hip/hip_runtime.h>

#define BB 128
#define TT 1024
#define II 256
#define HH 512
#define OO 256
#define KK 768

typedef _Float16 half8 __attribute__((ext_vector_type(8)));
typedef _Float16 half4v __attribute__((ext_vector_type(4)));
typedef float f32x4 __attribute__((ext_vector_type(4)));
typedef unsigned long long u64_t;

__device__ __forceinline__ float sigm(float x) { return 1.f / (1.f + __expf(-x)); }
__device__ __forceinline__ float tanhfast(float x) {
  float e = __expf(-2.f * fabsf(x));
  return copysignf((1.f - e) / (1.f + e), x);
}

// ---------- one-time: x [B][T][I] fp32 -> x16 [T][B][I] fp16 (R5-proven) ----------
__global__ void __launch_bounds__(64)
prep_x(const float* __restrict__ x, _Float16* __restrict__ x16)
{
  const int bid = blockIdx.x;          // t*BB + b
  const int b = bid & (BB - 1), t = bid >> 7;
  const int tid = threadIdx.x;
  float4 v = *(const float4*)(x + ((size_t)b * TT + t) * II + tid * 4);
  half4v h;
  h[0] = (_Float16)v.x; h[1] = (_Float16)v.y; h[2] = (_Float16)v.z; h[3] = (_Float16)v.w;
  *(half4v*)(x16 + (size_t)bid * II + tid * 4) = h;
}

// ---------- persistent LSTM (R7 base, ONE change) ----------
// grid=256 cooperative: 8 batch-group domains (16 rows) x 32 hidden-groups
// (16 units = 64 gate-cols; wave wn = gate wn). block=256 (4 waves).
// W fp16 fragments in registers (96 VGPR). ALL h payload moves via relaxed
// agent-scope ATOMICS: the sc-bits on the atomic instructions route them to
// the coherence point independent of fences (R6/R7-proven payload path).
// Flag store is RELEASE (orders h-stores before it; R2's relaxed flag raced).
// R10 change vs R7: consumer-side fence is WORKGROUP scope (compiler ordering
// only) instead of agent scope. R7's agent acquire ran buffer_inv (L1+XCD-L2
// invalidate) per WG per step, evicting x16/W -> 895 MB FETCH. Atomic loads
// don't need the invalidate; only R3-style plain loads did.
__global__ void __launch_bounds__(256, 1)
lstm_persist(const _Float16* __restrict__ x16,
             const float* __restrict__ Wf, const float* __restrict__ Wi,
             const float* __restrict__ Wc, const float* __restrict__ Wo,
             const float* __restrict__ bfp, const float* __restrict__ bip,
             const float* __restrict__ bcp, const float* __restrict__ bop,
             const float* __restrict__ Wlin, const float* __restrict__ blin,
             float* __restrict__ out,
             _Float16* __restrict__ hbuf,   // [2][BB][HH] fp16, atomic-only traffic
             int* __restrict__ flags)       // 256 slots x 64B, zeroed per launch
{
  __shared__ __align__(16) char hsb[16 * 1024];  // h_t staging [16 rows][512] fp16, swizzled
  __shared__ float pre[16 * 68];                 // [16 rows][64+pad] preacts

  const int gid = blockIdx.x;
  const int gb = gid >> 5, gh = gid & 31;
  const int tid = threadIdx.x;
  const int wn = tid >> 6, lane = tid & 63;      // wave index == gate index
  const int r = lane & 15, q = lane >> 4;

  // ---- one-time: W fragments fp32 -> fp16 registers ----
  const float* Wg = (wn == 0) ? Wf : (wn == 1) ? Wi : (wn == 2) ? Wc : Wo;
  const float* wsrc = Wg + (size_t)(gh * 16 + r) * KK + q * 8;
  half8 wfrag[24];
#pragma unroll
  for (int ks = 0; ks < 24; ++ks) {
    float4 w0 = *(const float4*)(wsrc + ks * 32);
    float4 w1 = *(const float4*)(wsrc + ks * 32 + 4);
    half8 h;
    h[0] = (_Float16)w0.x; h[1] = (_Float16)w0.y; h[2] = (_Float16)w0.z; h[3] = (_Float16)w0.w;
    h[4] = (_Float16)w1.x; h[5] = (_Float16)w1.y; h[6] = (_Float16)w1.z; h[7] = (_Float16)w1.w;
    wfrag[ks] = h;
  }

  // gate-update mapping: thread owns (row = tid>>4, unit = tid&15)
  const int grow = tid >> 4, gu = tid & 15;
  const int gcol = gh * 16 + gu;
  const float bfv = bfp[gcol], biv = bip[gcol], bcv = bcp[gcol], bov = bop[gcol];
  float C = 0.0f;

  const int arow = gb * 16 + r;                  // A batch row this lane feeds
  const int swz = (r & 7) << 4;                  // fragment-read swizzle

  // ================= time loop =================
  for (int t = 0; t < TT; ++t) {
    // x_t fragments (plain loads, issued before the barrier wait)
    const _Float16* xr = x16 + ((size_t)t * BB + arow) * II;
    half8 xa[8];
#pragma unroll
    for (int ks = 0; ks < 8; ++ks)
      xa[ks] = *(const half8*)(xr + ks * 32 + q * 8);

    if (t > 0) {
      // ---- wait for epoch t (h_t published domain-wide) ----
      if (wn == 0) {
        const int* fp = flags + (size_t)(gb * 32 + (lane & 31)) * 16;
        for (;;) {
          int v = __hip_atomic_load(fp, __ATOMIC_RELAXED, __HIP_MEMORY_SCOPE_AGENT);
          if (__all(v >= t)) break;
          __builtin_amdgcn_s_sleep(1);
        }
        __builtin_amdgcn_fence(__ATOMIC_ACQUIRE, "workgroup");  // compiler order only
      }
      __syncthreads();

      // ---- stage h_t (16 rows x 512) into swizzled LDS; atomic u64 loads ----
      {
        const int srow = tid >> 4, schunk = tid & 15;   // row, 32-half chunk
        const u64_t* hp = (const u64_t*)(hbuf + (size_t)(t & 1) * BB * HH +
                                         (size_t)(gb * 16 + srow) * HH + schunk * 32);
        char* dst = hsb + srow * 1024;
        const int cb = schunk * 64, sw = (srow & 7) << 4;
#pragma unroll
        for (int j = 0; j < 8; ++j) {
          u64_t v = __hip_atomic_load(hp + j, __ATOMIC_RELAXED, __HIP_MEMORY_SCOPE_AGENT);
          *(u64_t*)(dst + ((cb + j * 8) ^ sw)) = v;
        }
      }
      __syncthreads();
    }

    // ---- MFMA: pre[16 x 64] = A[16 x 768] * W^T (wave wn -> gate wn) ----
    f32x4 acc = {0.f, 0.f, 0.f, 0.f};
#pragma unroll
    for (int ks = 0; ks < 8; ++ks)
      acc = __builtin_amdgcn_mfma_f32_16x16x32_f16(xa[ks], wfrag[ks], acc, 0, 0, 0);
    if (t > 0) {
      const char* hrow = hsb + r * 1024;
#pragma unroll
      for (int ks = 0; ks < 16; ++ks) {
        half8 a = *(const half8*)(hrow + ((ks * 64 + q * 16) ^ swz));
        acc = __builtin_amdgcn_mfma_f32_16x16x32_f16(a, wfrag[8 + ks], acc, 0, 0, 0);
      }
    }
    // D layout: col = lane&15 (unit), row = q*4 + i
#pragma unroll
    for (int i = 0; i < 4; ++i)
      pre[(q * 4 + i) * 68 + wn * 16 + r] = acc[i];
    __syncthreads();

    // ---- gates + state update; pack 2 fp16 per relaxed agent u32 store ----
    {
      float pf = pre[grow * 68 + gu]      + bfv;
      float pi = pre[grow * 68 + 16 + gu] + biv;
      float pc = pre[grow * 68 + 32 + gu] + bcv;
      float po = pre[grow * 68 + 48 + gu] + bov;
      float fg = sigm(pf), ig = sigm(pi), og = sigm(po);
      float cg = tanhfast(pc);
      C = fg * C + ig * cg;
      float hn = og * tanhfast(C);
      unsigned hv;
      { _Float16 h16 = (_Float16)hn; hv = (unsigned)__builtin_bit_cast(unsigned short, h16); }
      unsigned other = (unsigned)__shfl_down((int)hv, 1);
      if (!(gu & 1)) {
        size_t ei = (size_t)((t + 1) & 1) * BB * HH +
                    (size_t)(gb * 16 + grow) * HH + gh * 16 + gu;
        __hip_atomic_store((unsigned*)hbuf + ei / 2, hv | (other << 16),
                           __ATOMIC_RELAXED, __HIP_MEMORY_SCOPE_AGENT);
      }
    }
    __syncthreads();  // compiler drains vmcnt before barrier -> h-stores complete
    if (tid == 0)
      __hip_atomic_store(flags + (size_t)gid * 16, t + 1,
                         __ATOMIC_RELEASE, __HIP_MEMORY_SCOPE_AGENT);
  }

  // ---- final domain barrier: epoch TT (h_T fully published) ----
  if (wn == 0) {
    const int* fp = flags + (size_t)(gb * 32 + (lane & 31)) * 16;
    for (;;) {
      int v = __hip_atomic_load(fp, __ATOMIC_RELAXED, __HIP_MEMORY_SCOPE_AGENT);
      if (__all(v >= TT)) break;
      __builtin_amdgcn_s_sleep(1);
    }
    __builtin_amdgcn_fence(__ATOMIC_ACQUIRE, "workgroup");
  }
  __syncthreads();

  // ===== epilogue (in-domain rows): out = h_T @ W_lin^T + b_lin =====
  {
    const int row = gb * 16 + (gh >> 1);   // this domain's rows only
    const int o0 = (gh & 1) * 128;
    // h_T is buffer 0 (last store at t=1023 -> buffer (t+1)&1 = 0)
    unsigned v = __hip_atomic_load((const unsigned*)hbuf + (size_t)row * (HH / 2) + tid,
                                   __ATOMIC_RELAXED, __HIP_MEMORY_SCOPE_AGENT);
    float* hf = (float*)hsb;
    hf[2 * tid]     = (float)__builtin_bit_cast(_Float16, (unsigned short)(v & 0xffffu));
    hf[2 * tid + 1] = (float)__builtin_bit_cast(_Float16, (unsigned short)(v >> 16));
    __syncthreads();
    if (tid < 128) {
      int o = o0 + tid;
      float a2 = blin[o];
      const float4* wr = (const float4*)(Wlin + (size_t)o * HH);
#pragma unroll 4
      for (int j = 0; j < 128; ++j) {
        float4 wv = wr[j];
        a2 += wv.x * hf[4 * j] + wv.y * hf[4 * j + 1] +
              wv.z * hf[4 * j + 2] + wv.w * hf[4 * j + 3];
      }
      out[(size_t)row * OO + o] = a2;
    }
  }
}

extern "C" void kernel_launch(void* const* d_in, const int* in_sizes, int n_in,
                              void* d_out, int out_size, void* d_ws, size_t ws_size,
                              hipStream_t stream) {
  const float* x    = (const float*)d_in[0];
  const float* Wf   = (const float*)d_in[1];
  const float* bf_  = (const float*)d_in[2];
  const float* Wi   = (const float*)d_in[3];
  const float* bi_  = (const float*)d_in[4];
  const float* Wc   = (const float*)d_in[5];
  const float* bc_  = (const float*)d_in[6];
  const float* Wo   = (const float*)d_in[7];
  const float* bo_  = (const float*)d_in[8];
  const float* Wlin = (const float*)d_in[9];
  const float* blin = (const float*)d_in[10];
  float* out = (float*)d_out;

  // ws: flags [0,16K) | hbuf [16K,16K+256K) | x16 [4M,4M+64M)  (71,303,168 B,
  // proven sufficient since R5/R6)
  int*      flags = (int*)d_ws;
  _Float16* hbuf  = (_Float16*)((char*)d_ws + 16384);
  _Float16* x16   = (_Float16*)((char*)d_ws + 4194304);

  hipMemsetAsync(d_ws, 0, 16384, stream);  // zero barrier flags every launch
  prep_x<<<dim3(TT * BB), dim3(64), 0, stream>>>(x, x16);

  void* args[] = {(void*)&x16, (void*)&Wf, (void*)&Wi, (void*)&Wc, (void*)&Wo,
                  (void*)&bf_, (void*)&bi_, (void*)&bc_, (void*)&bo_,
                  (void*)&Wlin, (void*)&blin, (void*)&out, (void*)&hbuf, (void*)&flags};
  hipLaunchCooperativeKernel((const void*)lstm_persist, dim3(256), dim3(256),
                             args, 0, stream);
}